// Round 8
// baseline (11997.626 us; speedup 1.0000x reference)
//
#include <hip/hip_runtime.h>

#define B_   16
#define T_   1600
#define D_   512
#define U_   1024
#define G_   4096
#define NWG  128            // 64 per direction, 16 units per WG
#define TPB  256
#define WSTR 776            // staging row stride (ushorts): 768 k + 8 pad
#define GSTR 68             // gates row stride (words)
#define XOFF 8704           // LDS: x image [16 b][512] bf16, row 1024B, ^((b&7)<<4)
#define HOFF 25088          // LDS: h image [16 b][1024] bf16, row 2048B, ^((b&7)<<4)
#define SMEM_BYTES 99328    // staging [64][WSTR] ushorts dominates

typedef __attribute__((ext_vector_type(8))) __bf16 bf16x8;
typedef __attribute__((ext_vector_type(4))) float  f32x4;
typedef __attribute__((ext_vector_type(2))) float  f32x2;
typedef __attribute__((ext_vector_type(8))) unsigned short us8v;
typedef unsigned long long u64;

__device__ __forceinline__ unsigned short f2bf(float f) {
  unsigned u = __builtin_bit_cast(unsigned, f);
  u += 0x7FFFu + ((u >> 16) & 1u);
  return (unsigned short)(u >> 16);
}
__device__ __forceinline__ bf16x8 cvt8(const float4 a, const float4 b) {
  us8v r;
  r[0]=f2bf(a.x); r[1]=f2bf(a.y); r[2]=f2bf(a.z); r[3]=f2bf(a.w);
  r[4]=f2bf(b.x); r[5]=f2bf(b.y); r[6]=f2bf(b.z); r[7]=f2bf(b.w);
  return __builtin_bit_cast(bf16x8, r);
}
__device__ __forceinline__ float sigm(float x){ return 1.f / (1.f + __expf(-x)); }
__device__ __forceinline__ float tanh_(float x){ return 1.f - 2.f / (__expf(2.f*x) + 1.f); }

__device__ __forceinline__ void stage_x(const float* __restrict__ x, int tg1,
                                        char* sm, int l) {
  const int sb  = l >> 2;             // batch row
  const int skb = (l & 3) << 3;       // float base within row
  const float* xs = x + ((size_t)sb*T_ + tg1)*D_;
  char* xd = sm + XOFF + sb*1024;
  const int ssz = (sb & 7) << 4;
  #pragma unroll
  for (int j = 0; j < 16; ++j) {
    int k = skb + j*32;
    float4 v0 = *(const float4*)(xs + k);
    float4 v1 = *(const float4*)(xs + k + 4);
    *(bf16x8*)(xd + ((k << 1) ^ ssz)) = cvt8(v0, v1);
  }
}

extern "C" __global__ void __launch_bounds__(TPB, 1)
bilstm_kernel(const float* __restrict__ x, const int* __restrict__ xlen,
              const float* __restrict__ kf, const float* __restrict__ rkf, const float* __restrict__ bf_,
              const float* __restrict__ kb, const float* __restrict__ rkb, const float* __restrict__ bb_,
              float* __restrict__ out, unsigned* __restrict__ flags,
              unsigned short* __restrict__ hbuf)
{
  extern __shared__ char smem[];

  const int tid  = threadIdx.x;
  const int wg   = blockIdx.x;
  const int dir  = wg >> 6;
  const int slot = wg & 63;
  const int u0   = slot << 4;         // 16 units per WG

  if (wg == 0 && tid < B_)
    out[(size_t)B_*T_*2*U_ + tid] = (float)xlen[tid];

  const float* Km = dir ? kb  : kf;
  const float* Rm = dir ? rkb : rkf;
  const float* Bv = dir ? bb_ : bf_;

  const int w = tid >> 6, l = tid & 63;
  const int ntile = w & 1, khalf = w >> 1;
  const int fr8 = (l >> 4) << 3;

  // ---- one-time: 2-phase weight staging + frag extraction ----
  // col c (0..63) = unit_local*4 + gate;  gc = gate*1024 + u0 + unit_local
  bf16x8 wx[2][4], wh[2][8];
  {
    unsigned short* stag = (unsigned short*)smem;
    for (int half = 0; half < 2; ++half) {
      for (int idx = tid; idx < 768*64; idx += TPB) {
        int kl = idx >> 6, c = idx & 63;
        int k = half*768 + kl;
        int gc = (c & 3)*1024 + u0 + (c >> 2);
        float wv = (k < D_) ? Km[(size_t)k*G_ + gc] : Rm[(size_t)(k-D_)*G_ + gc];
        stag[c*WSTR + kl] = f2bf(wv);
      }
      __syncthreads();
      #pragma unroll
      for (int t2 = 0; t2 < 2; ++t2) {
        int c = (ntile + t2*2)*16 + (l & 15);
        if (half == 0) {
          #pragma unroll
          for (int i = 0; i < 4; ++i) {
            int k = khalf*256 + i*64 + fr8;          // always < 512 -> half 0
            wx[t2][i] = *(const bf16x8*)(stag + c*WSTR + k);
          }
        }
        #pragma unroll
        for (int i = 0; i < 8; ++i) {
          int k = 512 + khalf*512 + i*64 + fr8;
          int hf = (k >= 768) ? 1 : 0;
          if (hf == half)
            wh[t2][i] = *(const bf16x8*)(stag + c*WSTR + (k - half*768));
        }
      }
      __syncthreads();
    }
  }

  float* gates = (float*)smem;        // [2 kh][16 b][GSTR] fp32 = 8704 B

  // epilogue-lane state (waves 0,1): 2 units each
  const int eb  = (w & 1)*8 + (l >> 3);
  const int eul = (l & 7) << 1;
  float bias[8];
  float cs0 = 0.f, cs1 = 0.f;
  if (w < 2) {
    #pragma unroll
    for (int g = 0; g < 4; ++g) {
      bias[g]     = Bv[g*1024 + u0 + eul];
      bias[4 + g] = Bv[g*1024 + u0 + eul + 1];
    }
  }

  unsigned* myflags = flags + dir*128;    // [0..63]=wave0 flags, [64..127]=wave1

  // MFMA-lane constants
  const int r = l & 15;
  const char* xr = smem + XOFF + r*1024;
  const char* hr = smem + HOFF + r*2048;
  const int sz = (r & 7) << 4;
  const int c0 = ntile*16 + (l & 15);
  const int c1 = c0 + 32;
  const int drow0 = (l >> 4) << 2;
  float* gp = gates + khalf*(16*GSTR);

  // prologue: stage x(t=0)
  if (w == 3) stage_x(x, dir ? (T_ - 1) : 0, smem, l);
  __syncthreads();

  for (int t = 0; t < T_; ++t) {
    const int tg = dir ? (T_ - 1 - t) : t;

    if (t > 0) {
      if (w == 2) {   // dedicated poller wave
        const unsigned tgt = (unsigned)t;
        long long guard = 0;
        for (;;) {
          unsigned a = __hip_atomic_load(myflags + l,      __ATOMIC_RELAXED, __HIP_MEMORY_SCOPE_AGENT);
          unsigned b = __hip_atomic_load(myflags + 64 + l, __ATOMIC_RELAXED, __HIP_MEMORY_SCOPE_AGENT);
          if (__all((a >= tgt) && (b >= tgt))) break;
          __builtin_amdgcn_s_sleep(1);
          if (++guard > (1LL << 22)) break;
        }
      }
      __syncthreads();   // S1: h(t-1) globally visible

      // cooperative coalesced h load -> LDS (swizzled), LLC-coherent
      {
        const u64* hsrc = (const u64*)(hbuf + ((size_t)((t & 1)*2 + dir) << 14));
        u64 tmp[16];
        #pragma unroll
        for (int j = 0; j < 16; ++j)
          tmp[j] = __hip_atomic_load(hsrc + tid + j*256, __ATOMIC_RELAXED, __HIP_MEMORY_SCOPE_AGENT);
        const int hb = (tid >> 2) & 15, hm = tid & 3, hs0 = tid >> 6;
        char* hd = smem + HOFF + hb*2048;
        const int hsz = (hb & 7) << 4;
        #pragma unroll
        for (int j = 0; j < 16; ++j)
          *(u64*)(hd + (((hs0 + 4*j)*32 + hm*8) ^ hsz)) = tmp[j];
      }
      __syncthreads();   // S2: h image staged
    }

    // MFMA phase: gates[b][64 cols] = [x(t) | h(t-1)] @ W  (khalf-split)
    {
      f32x4 aA = {0.f,0.f,0.f,0.f}, aB = aA, bA = aA, bB = aA;
      #pragma unroll
      for (int i = 0; i < 4; ++i) {
        bf16x8 av = *(const bf16x8*)(xr + (((khalf*256 + i*64 + fr8) << 1) ^ sz));
        if (i & 1) { aB = __builtin_amdgcn_mfma_f32_16x16x32_bf16(av, wx[0][i], aB, 0,0,0);
                     bB = __builtin_amdgcn_mfma_f32_16x16x32_bf16(av, wx[1][i], bB, 0,0,0); }
        else       { aA = __builtin_amdgcn_mfma_f32_16x16x32_bf16(av, wx[0][i], aA, 0,0,0);
                     bA = __builtin_amdgcn_mfma_f32_16x16x32_bf16(av, wx[1][i], bA, 0,0,0); }
      }
      if (t > 0) {
        #pragma unroll
        for (int i = 0; i < 8; ++i) {
          bf16x8 av = *(const bf16x8*)(hr + (((khalf*512 + i*64 + fr8) << 1) ^ sz));
          if (i & 1) { aB = __builtin_amdgcn_mfma_f32_16x16x32_bf16(av, wh[0][i], aB, 0,0,0);
                       bB = __builtin_amdgcn_mfma_f32_16x16x32_bf16(av, wh[1][i], bB, 0,0,0); }
          else       { aA = __builtin_amdgcn_mfma_f32_16x16x32_bf16(av, wh[0][i], aA, 0,0,0);
                       bA = __builtin_amdgcn_mfma_f32_16x16x32_bf16(av, wh[1][i], bA, 0,0,0); }
        }
      }
      aA += aB; bA += bB;
      #pragma unroll
      for (int j = 0; j < 4; ++j) {
        gp[(drow0 + j)*GSTR + c0] = aA[j];
        gp[(drow0 + j)*GSTR + c1] = bA[j];
      }
    }
    __syncthreads();   // S3: gates complete

    if (w < 2) {
      // epilogue: waves 0,1 (8 batches each), 2 units per lane
      const float* g0 = gates + eb*GSTR;
      const float* g1 = gates + (16 + eb)*GSTR;
      f32x4 u0a = *(const f32x4*)(g0 + eul*4);
      f32x4 u0b = *(const f32x4*)(g1 + eul*4);
      f32x4 u1a = *(const f32x4*)(g0 + eul*4 + 4);
      f32x4 u1b = *(const f32x4*)(g1 + eul*4 + 4);
      float gi0 = u0a[0]+u0b[0]+bias[0], gf0 = u0a[1]+u0b[1]+bias[1];
      float gz0 = u0a[2]+u0b[2]+bias[2], go0 = u0a[3]+u0b[3]+bias[3];
      float gi1 = u1a[0]+u1b[0]+bias[4], gf1 = u1a[1]+u1b[1]+bias[5];
      float gz1 = u1a[2]+u1b[2]+bias[6], go1 = u1a[3]+u1b[3]+bias[7];
      cs0 = sigm(gf0)*cs0 + sigm(gi0)*tanh_(gz0);
      cs1 = sigm(gf1)*cs1 + sigm(gi1)*tanh_(gz1);
      float h0 = sigm(go0)*tanh_(cs0);
      float h1 = sigm(go1)*tanh_(cs1);
      unsigned hp = ((unsigned)f2bf(h1) << 16) | (unsigned)f2bf(h0);
      unsigned* hdst = (unsigned*)(hbuf + ((size_t)(((t & 1) ^ 1)*2 + dir) << 14)
                                   + slot*256 + eb*16 + eul);
      __hip_atomic_store(hdst, hp, __ATOMIC_RELAXED, __HIP_MEMORY_SCOPE_AGENT);
      asm volatile("s_waitcnt vmcnt(0)" ::: "memory");   // h at LLC before flag
      if (l == 0)
        __hip_atomic_store(myflags + ((w & 1) ? 64 : 0) + slot, (unsigned)(t + 1),
                           __ATOMIC_RELAXED, __HIP_MEMORY_SCOPE_AGENT);
      f32x2 ho; ho.x = h0; ho.y = h1;   // out store off the critical path
      *(f32x2*)(out + ((size_t)eb*T_ + tg)*(2*U_) + (dir << 10) + u0 + eul) = ho;
    } else if (w == 3 && t + 1 < T_) {
      // stage x(t+1) in the epilogue shadow
      stage_x(x, dir ? (T_ - 2 - t) : (t + 1), smem, l);
    }
  }
}

extern "C" void kernel_launch(void* const* d_in, const int* in_sizes, int n_in,
                              void* d_out, int out_size, void* d_ws, size_t ws_size,
                              hipStream_t stream) {
  const float* x   = (const float*)d_in[0];
  const int*   xl  = (const int*)d_in[1];
  const float* kf  = (const float*)d_in[2];
  const float* rkf = (const float*)d_in[3];
  const float* bf_ = (const float*)d_in[4];
  const float* kb  = (const float*)d_in[5];
  const float* rkb = (const float*)d_in[6];
  const float* bb_ = (const float*)d_in[7];
  float* out = (float*)d_out;

  unsigned* flags = (unsigned*)d_ws;                              // 2 dir x 128 u32 = 1 KB
  unsigned short* hbuf = (unsigned short*)((char*)d_ws + 1024);   // 4 x 32 KB double buffers

  (void)hipMemsetAsync(d_ws, 0, 1024, stream);    // reset flags (graph-safe)

  bilstm_kernel<<<NWG, TPB, SMEM_BYTES, stream>>>(x, xl, kf, rkf, bf_, kb, rkb, bb_,
                                                  out, flags, hbuf);
}

// Round 9
// 5342.515 us; speedup vs baseline: 2.2457x; 2.2457x over previous
//
#include <hip/hip_runtime.h>

#define B_   16
#define T_   1600
#define D_   512
#define U_   1024
#define G_   4096           // 4*U
#define NWG  256            // 128 per direction, 1 per CU
#define TPB  256
#define KTOT 1536           // D + U
#define APAD 1544           // weight staging pad (ushort elems)
#define ROWB (APAD*2)
#define X16OFF (1 << 18)    // x16 image offset in d_ws (256 KB)

typedef __attribute__((ext_vector_type(8))) __bf16 bf16x8;
typedef __attribute__((ext_vector_type(4))) float  f32x4;
typedef __attribute__((ext_vector_type(2))) float  f32x2;
typedef __attribute__((ext_vector_type(8))) unsigned short us8v;
typedef unsigned long long u64;

__device__ __forceinline__ unsigned short f2bf(float f) {
  unsigned u = __builtin_bit_cast(unsigned, f);
  u += 0x7FFFu + ((u >> 16) & 1u);          // RNE
  return (unsigned short)(u >> 16);
}
__device__ __forceinline__ bf16x8 cvt8(const float4 a, const float4 b) {
  us8v r;
  r[0]=f2bf(a.x); r[1]=f2bf(a.y); r[2]=f2bf(a.z); r[3]=f2bf(a.w);
  r[4]=f2bf(b.x); r[5]=f2bf(b.y); r[6]=f2bf(b.z); r[7]=f2bf(b.w);
  return __builtin_bit_cast(bf16x8, r);
}
__device__ __forceinline__ float sigm(float x){ return 1.f / (1.f + __expf(-x)); }
__device__ __forceinline__ float tanh_(float x){ return 1.f - 2.f / (__expf(2.f*x) + 1.f); }

// one-time x fp32 -> bf16 (13,107,200 elems = 6400 blk * 256 thr * 8)
extern "C" __global__ void __launch_bounds__(256)
xcvt_kernel(const float* __restrict__ xin, unsigned short* __restrict__ x16) {
  const size_t i = ((size_t)blockIdx.x*256 + threadIdx.x) * 8;
  float4 a = *(const float4*)(xin + i);
  float4 b = *(const float4*)(xin + i + 4);
  *(us8v*)(x16 + i) = __builtin_bit_cast(us8v, cvt8(a, b));
}

extern "C" __global__ void __launch_bounds__(TPB, 1)
bilstm_kernel(const float* __restrict__ x, const int* __restrict__ xlen,
              const float* __restrict__ kf, const float* __restrict__ rkf, const float* __restrict__ bf_,
              const float* __restrict__ kb, const float* __restrict__ rkb, const float* __restrict__ bb_,
              float* __restrict__ out, unsigned* __restrict__ flags,
              unsigned short* __restrict__ hbuf,
              const unsigned short* __restrict__ x16, int use16)
{
  extern __shared__ char smem[];

  const int tid = threadIdx.x;
  const int wg  = blockIdx.x;
  const int dir = wg >> 7;
  const int slot = wg & 127;
  const int u0  = slot << 3;

  if (wg == 0 && tid < B_)
    out[(size_t)B_*T_*2*U_ + tid] = (float)xlen[tid];

  const float* Km = dir ? kb  : kf;
  const float* Rm = dir ? rkb : rkf;
  const float* Bv = dir ? bb_ : bf_;

  const int w = tid >> 6, l = tid & 63;
  const int ntile = w & 1, khalf = w >> 1;

  // ---- one-time: stage weight slice [1536][32] -> LDS bf16 ----
  {
    char* Wb = smem;
    for (int i = tid; i < KTOT*32; i += TPB) {
      int k = i >> 5, c = i & 31;
      int gc = ((c >> 3) << 10) + u0 + (c & 7);
      float wv = (k < D_) ? Km[(size_t)k*G_ + gc] : Rm[(size_t)(k-D_)*G_ + gc];
      *(unsigned short*)(Wb + c*ROWB + (k << 1)) = f2bf(wv);
    }
  }
  __syncthreads();

  // ---- one-time: pull 24 B-fragments into VGPRs ----
  bf16x8 wx[8], wh[16];
  {
    const char* Brow = smem + (ntile*16 + (l & 15))*ROWB + ((l >> 4) << 4);
    #pragma unroll
    for (int i = 0; i < 8; ++i)  wx[i] = *(const bf16x8*)(Brow + ((khalf*8 + i) << 6));
    #pragma unroll
    for (int i = 0; i < 16; ++i) wh[i] = *(const bf16x8*)(Brow + ((16 + khalf*16 + i) << 6));
  }
  __syncthreads();   // weight LDS dead; reuse: gates @0 (4KB), h-stage @4096 (32KB)

  float* gates = (float*)smem;            // [2 khalf][16 b][32 col]
  char*  hst   = smem + 4096;             // [16 b][2048 B] XOR-swizzled bf16 h
  float* gp    = gates + khalf*512;
  const int drow0 = (l >> 4) << 2, dcol = ntile*16 + (l & 15);

  // epilogue-lane state (wave 0): 2 units each
  const int eb = tid >> 2, eup = (tid & 3) << 1;
  float bi0=0, bi1=0, bff0=0, bff1=0, bz0=0, bz1=0, bo0=0, bo1=0, c0=0, c1=0;
  if (tid < 64) {
    bi0 = Bv[u0+eup];        bi1 = Bv[u0+eup+1];
    bff0= Bv[1024+u0+eup];   bff1= Bv[1024+u0+eup+1];
    bz0 = Bv[2048+u0+eup];   bz1 = Bv[2048+u0+eup+1];
    bo0 = Bv[3072+u0+eup];   bo1 = Bv[3072+u0+eup+1];
  }

  unsigned* myflags = flags + dir*128;

  // per-lane x bases (fp32 fallback and bf16 fast path)
  const float* xbase = x + (size_t)(l & 15)*T_*D_ + khalf*256 + ((l >> 4) << 3);
  const unsigned short* x16b = x16 + (size_t)(l & 15)*T_*D_ + khalf*256 + ((l >> 4) << 3);

  // A-frag LDS read base for h: row = l&15; swizzle XOR (row&7)<<4
  const char* hrow  = hst + (l & 15)*2048;
  const int   kbase = (khalf*512 + ((l >> 4) << 3)) << 1;
  const int   swz   = ((l & 15) & 7) << 4;

  // prologue: x-projection for t=0
  f32x4 acc = {0.f, 0.f, 0.f, 0.f};
  {
    const int tg0 = dir ? (T_ - 1) : 0;
    if (use16) {
      const unsigned short* xA = x16b + (size_t)tg0 * D_;
      #pragma unroll
      for (int i = 0; i < 8; ++i)
        acc = __builtin_amdgcn_mfma_f32_16x16x32_bf16(*(const bf16x8*)(xA + i*32), wx[i], acc, 0, 0, 0);
    } else {
      const float* xA = xbase + (size_t)tg0 * D_;
      #pragma unroll
      for (int i = 0; i < 8; ++i) {
        float4 lo = *(const float4*)(xA + i*32);
        float4 hi = *(const float4*)(xA + i*32 + 4);
        acc = __builtin_amdgcn_mfma_f32_16x16x32_bf16(cvt8(lo, hi), wx[i], acc, 0, 0, 0);
      }
    }
  }

  for (int t = 0; t < T_; ++t) {
    const int tg = dir ? (T_ - 1 - t) : t;

    if (t > 0) {
      // fine-grained poll: each thread waits only on ITS producer slot (tid>>1)
      {
        const unsigned tgt = (unsigned)t;
        long long guard = 0;
        while (__hip_atomic_load(myflags + (tid >> 1), __ATOMIC_RELAXED, __HIP_MEMORY_SCOPE_AGENT) < tgt) {
          __builtin_amdgcn_s_sleep(1);
          if (++guard > (1LL << 22)) break;
        }
      }
      // cooperative coalesced h load -> LDS (swizzled), LLC-coherent
      {
        const u64* hsrc = (const u64*)(hbuf + (((size_t)((t & 1)*2 + dir)) << 14));
        u64 tmp[16];
        #pragma unroll
        for (int j = 0; j < 16; ++j)
          tmp[j] = __hip_atomic_load(hsrc + tid + j*256, __ATOMIC_RELAXED, __HIP_MEMORY_SCOPE_AGENT);
        #pragma unroll
        for (int j = 0; j < 16; ++j)
          *(u64*)(hst + j*2048 + ((tid << 3) ^ ((j & 7) << 4))) = tmp[j];
      }
      __syncthreads();   // S2: h image staged

      // recurrent MFMAs from LDS; 2 accumulators break the dep chain
      f32x4 acc2 = {0.f, 0.f, 0.f, 0.f};
      #pragma unroll
      for (int i = 0; i < 16; i += 2) {
        bf16x8 a0 = *(const bf16x8*)(hrow + ((kbase + i*64)     ^ swz));
        bf16x8 a1 = *(const bf16x8*)(hrow + ((kbase + (i+1)*64) ^ swz));
        acc  = __builtin_amdgcn_mfma_f32_16x16x32_bf16(a0, wh[i],   acc,  0, 0, 0);
        acc2 = __builtin_amdgcn_mfma_f32_16x16x32_bf16(a1, wh[i+1], acc2, 0, 0, 0);
      }
      acc[0]+=acc2[0]; acc[1]+=acc2[1]; acc[2]+=acc2[2]; acc[3]+=acc2[3];
    }

    #pragma unroll
    for (int j = 0; j < 4; ++j) gp[(drow0 + j)*32 + dcol] = acc[j];
    __syncthreads();   // S3: gates ready; h-image reads done

    // epilogue: wave 0. Order: h-store -> drain -> flag -> out (off-path)
    if (tid < 64) {
      const float* g0 = gates + eb*32 + eup;
      float gi0 = g0[0]  + g0[512] + bi0,  gi1 = g0[1]  + g0[513] + bi1;
      float gf0 = g0[8]  + g0[520] + bff0, gf1 = g0[9]  + g0[521] + bff1;
      float gz0 = g0[16] + g0[528] + bz0,  gz1 = g0[17] + g0[529] + bz1;
      float go0 = g0[24] + g0[536] + bo0,  go1 = g0[25] + g0[537] + bo1;
      c0 = sigm(gf0)*c0 + sigm(gi0)*tanh_(gz0);
      c1 = sigm(gf1)*c1 + sigm(gi1)*tanh_(gz1);
      float h0 = sigm(go0)*tanh_(c0);
      float h1 = sigm(go1)*tanh_(c1);
      unsigned hp = ((unsigned)f2bf(h1) << 16) | (unsigned)f2bf(h0);
      unsigned* hdst = (unsigned*)(hbuf + (((size_t)(((t & 1) ^ 1)*2 + dir)) << 14) + (eb << 10) + u0 + eup);
      __hip_atomic_store(hdst, hp, __ATOMIC_RELAXED, __HIP_MEMORY_SCOPE_AGENT);
      asm volatile("s_waitcnt vmcnt(0)" ::: "memory");   // h at LLC before flag
      if (tid == 0)
        __hip_atomic_store(myflags + slot, (unsigned)(t + 1), __ATOMIC_RELAXED, __HIP_MEMORY_SCOPE_AGENT);
      f32x2 ho; ho.x = h0; ho.y = h1;   // out store off the critical path, cached
      *(f32x2*)(out + ((size_t)eb*T_ + tg)*(2*U_) + (dir << 10) + u0 + eup) = ho;
    }

    if (t + 1 < T_) {
      // x-projection for t+1 (cheap on bf16 path; overlaps flag propagation)
      const int tg1 = dir ? (T_ - 2 - t) : (t + 1);
      f32x4 nacc = {0.f, 0.f, 0.f, 0.f};
      if (use16) {
        const unsigned short* xA = x16b + (size_t)tg1 * D_;
        #pragma unroll
        for (int i = 0; i < 8; ++i)
          nacc = __builtin_amdgcn_mfma_f32_16x16x32_bf16(*(const bf16x8*)(xA + i*32), wx[i], nacc, 0, 0, 0);
      } else {
        const float* xA = xbase + (size_t)tg1 * D_;
        #pragma unroll
        for (int i = 0; i < 8; ++i) {
          float4 lo = *(const float4*)(xA + i*32);
          float4 hi = *(const float4*)(xA + i*32 + 4);
          nacc = __builtin_amdgcn_mfma_f32_16x16x32_bf16(cvt8(lo, hi), wx[i], nacc, 0, 0, 0);
        }
      }
      acc = nacc;
    }
  }
}

extern "C" void kernel_launch(void* const* d_in, const int* in_sizes, int n_in,
                              void* d_out, int out_size, void* d_ws, size_t ws_size,
                              hipStream_t stream) {
  const float* x   = (const float*)d_in[0];
  const int*   xl  = (const int*)d_in[1];
  const float* kf  = (const float*)d_in[2];
  const float* rkf = (const float*)d_in[3];
  const float* bf_ = (const float*)d_in[4];
  const float* kb  = (const float*)d_in[5];
  const float* rkb = (const float*)d_in[6];
  const float* bb_ = (const float*)d_in[7];
  float* out = (float*)d_out;

  unsigned* flags = (unsigned*)d_ws;                              // 2 x 128 u32
  unsigned short* hbuf = (unsigned short*)((char*)d_ws + 1024);   // 4 x 32 KB
  unsigned short* x16  = (unsigned short*)((char*)d_ws + X16OFF); // 26.2 MB bf16 x

  const size_t need = (size_t)X16OFF + (size_t)B_*T_*D_*2;
  const int use16 = (ws_size >= need) ? 1 : 0;

  (void)hipMemsetAsync(d_ws, 0, 1024, stream);    // reset flags (graph-safe)
  if (use16)
    xcvt_kernel<<<6400, 256, 0, stream>>>(x, x16);

  const size_t smem = 32*(size_t)ROWB;   // 98,816 B (weight staging); runtime uses 36,864 B
  bilstm_kernel<<<NWG, TPB, smem, stream>>>(x, xl, kf, rkf, bf_, kb, rkb, bb_,
                                            out, flags, hbuf, x16, use16);
}

// Round 10
// 5189.930 us; speedup vs baseline: 2.3117x; 1.0294x over previous
//
#include <hip/hip_runtime.h>

#define B_   16
#define T_   1600
#define D_   512
#define U_   1024
#define G_   4096           // 4*U
#define NWG  256            // 128 per direction, 1 per CU
#define TPB  256
#define KTOT 1536           // D + U
#define APAD 1544           // weight staging pad (ushort elems)
#define ROWB (APAD*2)
#define X16OFF (1 << 18)    // x16 image offset in d_ws; hbuf32 = 4 x 64KB fills [0, 256KB)

typedef __attribute__((ext_vector_type(8))) __bf16 bf16x8;
typedef __attribute__((ext_vector_type(4))) float  f32x4;
typedef __attribute__((ext_vector_type(2))) float  f32x2;
typedef __attribute__((ext_vector_type(4))) unsigned int uint4v;
typedef __attribute__((ext_vector_type(8))) unsigned short us8v;
typedef unsigned long long u64;
typedef unsigned int u32;

__device__ __forceinline__ unsigned short f2bf(float f) {
  unsigned u = __builtin_bit_cast(unsigned, f);
  u += 0x7FFFu + ((u >> 16) & 1u);          // RNE
  return (unsigned short)(u >> 16);
}
__device__ __forceinline__ bf16x8 cvt8(const float4 a, const float4 b) {
  us8v r;
  r[0]=f2bf(a.x); r[1]=f2bf(a.y); r[2]=f2bf(a.z); r[3]=f2bf(a.w);
  r[4]=f2bf(b.x); r[5]=f2bf(b.y); r[6]=f2bf(b.z); r[7]=f2bf(b.w);
  return __builtin_bit_cast(bf16x8, r);
}
__device__ __forceinline__ float sigm(float x){ return 1.f / (1.f + __expf(-x)); }
__device__ __forceinline__ float tanh_(float x){ return 1.f - 2.f / (__expf(2.f*x) + 1.f); }

// one-time x fp32 -> bf16
extern "C" __global__ void __launch_bounds__(256)
xcvt_kernel(const float* __restrict__ xin, unsigned short* __restrict__ x16) {
  const size_t i = ((size_t)blockIdx.x*256 + threadIdx.x) * 8;
  float4 a = *(const float4*)(xin + i);
  float4 b = *(const float4*)(xin + i + 4);
  *(us8v*)(x16 + i) = __builtin_bit_cast(us8v, cvt8(a, b));
}

extern "C" __global__ void __launch_bounds__(TPB, 1)
bilstm_kernel(const float* __restrict__ x, const int* __restrict__ xlen,
              const float* __restrict__ kf, const float* __restrict__ rkf, const float* __restrict__ bf_,
              const float* __restrict__ kb, const float* __restrict__ rkb, const float* __restrict__ bb_,
              float* __restrict__ out, u32* __restrict__ hbuf32,
              const unsigned short* __restrict__ x16, int use16)
{
  extern __shared__ char smem[];

  const int tid = threadIdx.x;
  const int wg  = blockIdx.x;
  const int dir = wg >> 7;
  const int slot = wg & 127;
  const int u0  = slot << 3;

  if (wg == 0 && tid < B_)
    out[(size_t)B_*T_*2*U_ + tid] = (float)xlen[tid];

  const float* Km = dir ? kb  : kf;
  const float* Rm = dir ? rkb : rkf;
  const float* Bv = dir ? bb_ : bf_;

  const int w = tid >> 6, l = tid & 63;
  const int ntile = w & 1, khalf = w >> 1;

  // ---- one-time: stage weight slice [1536][32] -> LDS bf16 ----
  {
    char* Wb = smem;
    for (int i = tid; i < KTOT*32; i += TPB) {
      int k = i >> 5, c = i & 31;
      int gc = ((c >> 3) << 10) + u0 + (c & 7);
      float wv = (k < D_) ? Km[(size_t)k*G_ + gc] : Rm[(size_t)(k-D_)*G_ + gc];
      *(unsigned short*)(Wb + c*ROWB + (k << 1)) = f2bf(wv);
    }
  }
  __syncthreads();

  // ---- one-time: pull 24 B-fragments into VGPRs ----
  bf16x8 wx[8], wh[16];
  {
    const char* Brow = smem + (ntile*16 + (l & 15))*ROWB + ((l >> 4) << 4);
    #pragma unroll
    for (int i = 0; i < 8; ++i)  wx[i] = *(const bf16x8*)(Brow + ((khalf*8 + i) << 6));
    #pragma unroll
    for (int i = 0; i < 16; ++i) wh[i] = *(const bf16x8*)(Brow + ((16 + khalf*16 + i) << 6));
  }
  __syncthreads();   // weight LDS dead; reuse: gates @0 (4KB), h-stage @4096 (32KB)

  float* gates = (float*)smem;            // [2 khalf][16 b][32 col]
  char*  hst   = smem + 4096;             // [16 b][2048 B] XOR-swizzled bf16 h
  float* gp    = gates + khalf*512;
  const int drow0 = (l >> 4) << 2, dcol = ntile*16 + (l & 15);

  // epilogue-lane state (wave 0): 2 units each
  const int eb = tid >> 2, eup = (tid & 3) << 1;
  float bi0=0, bi1=0, bff0=0, bff1=0, bz0=0, bz1=0, bo0=0, bo1=0, c0=0, c1=0;
  if (tid < 64) {
    bi0 = Bv[u0+eup];        bi1 = Bv[u0+eup+1];
    bff0= Bv[1024+u0+eup];   bff1= Bv[1024+u0+eup+1];
    bz0 = Bv[2048+u0+eup];   bz1 = Bv[2048+u0+eup+1];
    bo0 = Bv[3072+u0+eup];   bo1 = Bv[3072+u0+eup+1];
  }

  // per-lane x bases
  const float* xbase = x + (size_t)(l & 15)*T_*D_ + khalf*256 + ((l >> 4) << 3);
  const unsigned short* x16b = x16 + (size_t)(l & 15)*T_*D_ + khalf*256 + ((l >> 4) << 3);

  // A-frag LDS read base for h
  const char* hrow  = hst + (l & 15)*2048;
  const int   kbase = (khalf*512 + ((l >> 4) << 3)) << 1;
  const int   swz   = ((l & 15) & 7) << 4;

  const unsigned off0 = (unsigned)tid * 16;   // consumer poll byte offsets: off0 + j*4096

  // prologue: x-projection for t=0
  f32x4 acc = {0.f, 0.f, 0.f, 0.f};
  {
    const int tg0 = dir ? (T_ - 1) : 0;
    if (use16) {
      const unsigned short* xA = x16b + (size_t)tg0 * D_;
      #pragma unroll
      for (int i = 0; i < 8; ++i)
        acc = __builtin_amdgcn_mfma_f32_16x16x32_bf16(*(const bf16x8*)(xA + i*32), wx[i], acc, 0, 0, 0);
    } else {
      const float* xA = xbase + (size_t)tg0 * D_;
      #pragma unroll
      for (int i = 0; i < 8; ++i) {
        float4 lo = *(const float4*)(xA + i*32);
        float4 hi = *(const float4*)(xA + i*32 + 4);
        acc = __builtin_amdgcn_mfma_f32_16x16x32_bf16(cvt8(lo, hi), wx[i], acc, 0, 0, 0);
      }
    }
  }

  for (int t = 0; t < T_; ++t) {
    const int tg = dir ? (T_ - 1 - t) : t;

    if (t > 0) {
      // ---- fused poll+load: tagged h image, retry until all tags == t ----
      const u32* hb = hbuf32 + (size_t)((t & 1)*2 + dir) * 16384;
      const unsigned tagv = (unsigned)t << 16;
      uint4v hv[16];
      long long guard = 0;
      for (;;) {
        #pragma unroll
        for (int j = 0; j < 16; ++j)
          asm volatile("global_load_dwordx4 %0, %1, %2 sc0 sc1"
                       : "=v"(hv[j]) : "v"(off0 + (unsigned)(j*4096)), "s"(hb));
        asm volatile("s_waitcnt vmcnt(0)" ::: "memory");
        __builtin_amdgcn_sched_barrier(0);
        unsigned bad = 0;
        #pragma unroll
        for (int j = 0; j < 16; ++j)
          bad |= (hv[j][0] ^ tagv) | (hv[j][2] ^ tagv);   // one tag per 8B producer granule
        if (!(bad & 0xFFFF0000u)) break;
        __builtin_amdgcn_s_sleep(1);
        if (++guard > (1LL << 22)) break;
      }
      // strip tags, pack bf16 pairs, stage to LDS (swizzled)
      #pragma unroll
      for (int j = 0; j < 16; ++j) {
        u32 lo = __builtin_amdgcn_perm(hv[j][1], hv[j][0], 0x05040100u);
        u32 hi = __builtin_amdgcn_perm(hv[j][3], hv[j][2], 0x05040100u);
        u64 v = ((u64)hi << 32) | lo;
        *(u64*)(hst + j*2048 + ((tid << 3) ^ ((j & 7) << 4))) = v;
      }
      __syncthreads();   // S2: h image staged

      // recurrent MFMAs from LDS; 2 accumulators break the dep chain
      f32x4 acc2 = {0.f, 0.f, 0.f, 0.f};
      #pragma unroll
      for (int i = 0; i < 16; i += 2) {
        bf16x8 a0 = *(const bf16x8*)(hrow + ((kbase + i*64)     ^ swz));
        bf16x8 a1 = *(const bf16x8*)(hrow + ((kbase + (i+1)*64) ^ swz));
        acc  = __builtin_amdgcn_mfma_f32_16x16x32_bf16(a0, wh[i],   acc,  0, 0, 0);
        acc2 = __builtin_amdgcn_mfma_f32_16x16x32_bf16(a1, wh[i+1], acc2, 0, 0, 0);
      }
      acc[0]+=acc2[0]; acc[1]+=acc2[1]; acc[2]+=acc2[2]; acc[3]+=acc2[3];
    }

    #pragma unroll
    for (int j = 0; j < 4; ++j) gp[(drow0 + j)*32 + dcol] = acc[j];
    __syncthreads();   // S3: gates ready; h-image reads done

    // epilogue: wave 0. Tagged h store is self-publishing: no drain, no flag.
    if (tid < 64) {
      const float* g0 = gates + eb*32 + eup;
      float gi0 = g0[0]  + g0[512] + bi0,  gi1 = g0[1]  + g0[513] + bi1;
      float gf0 = g0[8]  + g0[520] + bff0, gf1 = g0[9]  + g0[521] + bff1;
      float gz0 = g0[16] + g0[528] + bz0,  gz1 = g0[17] + g0[529] + bz1;
      float go0 = g0[24] + g0[536] + bo0,  go1 = g0[25] + g0[537] + bo1;
      c0 = sigm(gf0)*c0 + sigm(gi0)*tanh_(gz0);
      c1 = sigm(gf1)*c1 + sigm(gi1)*tanh_(gz1);
      float h0 = sigm(go0)*tanh_(c0);
      float h1 = sigm(go1)*tanh_(c1);
      const unsigned tagw = (unsigned)(t + 1) << 16;
      u32 w0 = (u32)f2bf(h0) | tagw;
      u32 w1 = (u32)f2bf(h1) | tagw;
      u32* hdst = hbuf32 + (size_t)(((t & 1) ^ 1)*2 + dir)*16384 + (eb << 10) + u0 + eup;
      __hip_atomic_store((u64*)hdst, ((u64)w1 << 32) | w0, __ATOMIC_RELAXED, __HIP_MEMORY_SCOPE_AGENT);
      f32x2 ho; ho.x = h0; ho.y = h1;   // out store off the critical path, cached
      *(f32x2*)(out + ((size_t)eb*T_ + tg)*(2*U_) + (dir << 10) + u0 + eup) = ho;
    }

    if (t + 1 < T_) {
      // x-projection for t+1 (overlaps h-store propagation)
      const int tg1 = dir ? (T_ - 2 - t) : (t + 1);
      f32x4 nacc = {0.f, 0.f, 0.f, 0.f};
      if (use16) {
        const unsigned short* xA = x16b + (size_t)tg1 * D_;
        #pragma unroll
        for (int i = 0; i < 8; ++i)
          nacc = __builtin_amdgcn_mfma_f32_16x16x32_bf16(*(const bf16x8*)(xA + i*32), wx[i], nacc, 0, 0, 0);
      } else {
        const float* xA = xbase + (size_t)tg1 * D_;
        #pragma unroll
        for (int i = 0; i < 8; ++i) {
          float4 lo = *(const float4*)(xA + i*32);
          float4 hi = *(const float4*)(xA + i*32 + 4);
          nacc = __builtin_amdgcn_mfma_f32_16x16x32_bf16(cvt8(lo, hi), wx[i], nacc, 0, 0, 0);
        }
      }
      acc = nacc;
    }
  }
}

extern "C" void kernel_launch(void* const* d_in, const int* in_sizes, int n_in,
                              void* d_out, int out_size, void* d_ws, size_t ws_size,
                              hipStream_t stream) {
  const float* x   = (const float*)d_in[0];
  const int*   xl  = (const int*)d_in[1];
  const float* kf  = (const float*)d_in[2];
  const float* rkf = (const float*)d_in[3];
  const float* bf_ = (const float*)d_in[4];
  const float* kb  = (const float*)d_in[5];
  const float* rkb = (const float*)d_in[6];
  const float* bb_ = (const float*)d_in[7];
  float* out = (float*)d_out;

  u32* hbuf32 = (u32*)d_ws;                                       // 4 x 64KB tagged h images
  unsigned short* x16 = (unsigned short*)((char*)d_ws + X16OFF);  // 26.2 MB bf16 x

  const size_t need = (size_t)X16OFF + (size_t)B_*T_*D_*2;
  const int use16 = (ws_size >= need) ? 1 : 0;

  (void)hipMemsetAsync(d_ws, 0, X16OFF, stream);    // zero all tags (graph-safe)
  if (use16)
    xcvt_kernel<<<6400, 256, 0, stream>>>(x, x16);

  const size_t smem = 32*(size_t)ROWB;   // 98,816 B (weight staging); runtime uses 36,864 B
  bilstm_kernel<<<NWG, TPB, smem, stream>>>(x, xl, kf, rkf, bf_, kb, rkb, bb_,
                                            out, hbuf32, x16, use16);
}